// Round 1
// baseline (353.328 us; speedup 1.0000x reference)
//
#include <hip/hip_runtime.h>
#include <hip/hip_bf16.h>
#include <stdint.h>

#define B_ 4
#define H_ 16
#define L_ 2048
#define D_ 64
#define BH (B_ * H_)

typedef __attribute__((ext_vector_type(8))) short short8;
typedef __attribute__((ext_vector_type(4))) float f32x4;

__device__ __forceinline__ short b16(float f) {
  __hip_bfloat16 h = __float2bfloat16(f);
  return __builtin_bit_cast(short, h);
}

// ---- prepass: V [bh][k][d] fp32 -> Vt [bh][d][k] bf16 (transposed) ----
__global__ __launch_bounds__(256) void vt_kernel(const float* __restrict__ V,
                                                 unsigned short* __restrict__ Vt) {
  __shared__ unsigned short lds[64 * 68];  // [k][d], stride 68 to break bank conflicts
  int bid = blockIdx.x;
  int bh  = bid >> 5;
  int kt  = bid & 31;
  int t   = threadIdx.x;
  const float* vsrc = V + ((size_t)bh * L_ + (size_t)kt * 64) * D_;
#pragma unroll
  for (int i = 0; i < 4; ++i) {
    int f4  = i * 256 + t;
    int row = f4 >> 4;
    int c4  = (f4 & 15) << 2;
    float4 v = *reinterpret_cast<const float4*>(vsrc + row * D_ + c4);
    ushort4 u;
    u.x = (unsigned short)b16(v.x);
    u.y = (unsigned short)b16(v.y);
    u.z = (unsigned short)b16(v.z);
    u.w = (unsigned short)b16(v.w);
    *reinterpret_cast<ushort4*>(&lds[row * 68 + c4]) = u;
  }
  __syncthreads();
  unsigned short* dst = Vt + (size_t)bh * D_ * L_ + (size_t)kt * 64;
#pragma unroll
  for (int i = 0; i < 8; ++i) {
    int c  = i * 256 + t;
    int d  = c >> 5;
    int k2 = (c & 31) * 2;
    unsigned int lo = lds[(k2 + 0) * 68 + d];
    unsigned int hi = lds[(k2 + 1) * 68 + d];
    *reinterpret_cast<unsigned int*>(dst + d * L_ + k2) = lo | (hi << 16);
  }
}

// ---- fused sigmoid-attention ----
// one block = one (b,h, q-tile of 64); 4 waves in 2x2 quadrants; k-loop in tiles of 64
__global__ __launch_bounds__(256) void attn_kernel(
    const float* __restrict__ Q, const float* __restrict__ K,
    const int* __restrict__ M, const unsigned short* __restrict__ Vt,
    float* __restrict__ O, float* __restrict__ A) {
  // all [64][64] bf16 tiles, XOR-swizzled: element (row,col) at row*64 + (col ^ ((row&7)<<3))
  __shared__ unsigned short Kl[64 * 64];  // K tile [k][d]
  __shared__ unsigned short Vl[64 * 64];  // V^T tile [d][k]
  __shared__ unsigned short Pl[64 * 64];  // P (bf16 sigmoid) [q][k]

  int wg  = blockIdx.x;
  int swz = (wg & 7) * 256 + (wg >> 3);  // bijective XCD swizzle (2048 % 8 == 0)
  int bh  = swz >> 5;
  int qt  = swz & 31;

  int t    = threadIdx.x;
  int lane = t & 63;
  int w    = t >> 6;
  int wr   = w >> 1;   // wave row quadrant (q)
  int wc   = w & 1;    // wave col quadrant (k for S, d for O)
  int lr   = lane & 15;
  int lg   = lane >> 4;

  // ---- Q fragments, hoisted (fp32 -> bf16 in regs) ----
  short8 qf[2][2];  // [m][ks]
  const float* qbase = Q + ((size_t)bh * L_ + (size_t)qt * 64 + wr * 32) * D_;
#pragma unroll
  for (int m = 0; m < 2; ++m) {
#pragma unroll
    for (int ks = 0; ks < 2; ++ks) {
      const float4* p = reinterpret_cast<const float4*>(qbase + (m * 16 + lr) * D_ + ks * 32 + lg * 8);
      float4 a = p[0], b = p[1];
      qf[m][ks] = (short8){b16(a.x), b16(a.y), b16(a.z), b16(a.w),
                           b16(b.x), b16(b.y), b16(b.z), b16(b.w)};
    }
  }

  f32x4 o[2][2] = {};  // O accumulator (q quadrant wr, d quadrant wc)
  const int* mbase = M + (size_t)(bh >> 4) * L_ * L_;
  float* abase = A + (size_t)bh * L_ * L_;
  const float* kbase0 = K + (size_t)bh * L_ * D_;
  const unsigned short* vbase0 = Vt + (size_t)bh * D_ * L_;
  int qrow = qt * 64 + wr * 32;

  for (int ki = 0; ki < 32; ++ki) {
    int k0 = ki * 64;

    // mask prefetch (independent of LDS; overlaps staging + MFMA)
    int mv[2][2][4];
#pragma unroll
    for (int m = 0; m < 2; ++m)
#pragma unroll
      for (int n = 0; n < 2; ++n)
#pragma unroll
        for (int r = 0; r < 4; ++r)
          mv[m][n][r] = mbase[(size_t)(qrow + m * 16 + lg * 4 + r) * L_ + k0 + wc * 32 + n * 16 + lr];

    __syncthreads();  // previous iter's LDS readers done

    // ---- stage K tile (fp32 -> bf16, swizzled) ----
    const float* ksrc = kbase0 + (size_t)k0 * D_;
#pragma unroll
    for (int i = 0; i < 4; ++i) {
      int f4  = i * 256 + t;
      int row = f4 >> 4;
      int c4  = (f4 & 15) << 2;
      float4 v = *reinterpret_cast<const float4*>(ksrc + row * D_ + c4);
      ushort4 u;
      u.x = (unsigned short)b16(v.x);
      u.y = (unsigned short)b16(v.y);
      u.z = (unsigned short)b16(v.z);
      u.w = (unsigned short)b16(v.w);
      *reinterpret_cast<ushort4*>(&Kl[row * 64 + (c4 ^ ((row & 7) << 3))]) = u;
    }
    // ---- stage V^T tile (bf16, swizzled) ----
    const unsigned short* vsrc = vbase0 + k0;
#pragma unroll
    for (int i = 0; i < 2; ++i) {
      int g   = i * 256 + t;
      int row = g >> 3;
      int c0  = (g & 7) << 3;
      uint4 v = *reinterpret_cast<const uint4*>(vsrc + (size_t)row * L_ + c0);
      *reinterpret_cast<uint4*>(&Vl[row * 64 + (c0 ^ ((row & 7) << 3))]) = v;
    }
    __syncthreads();

    // ---- S = Q K^T (wave quadrant: rows wr*32+, cols wc*32+) ----
    f32x4 s[2][2] = {};
#pragma unroll
    for (int ks = 0; ks < 2; ++ks) {
      short8 kf[2];
#pragma unroll
      for (int n = 0; n < 2; ++n) {
        int row = wc * 32 + n * 16 + lr;   // key index
        int col = ks * 32 + lg * 8;        // d
        kf[n] = *reinterpret_cast<const short8*>(&Kl[row * 64 + (col ^ ((row & 7) << 3))]);
      }
#pragma unroll
      for (int m = 0; m < 2; ++m)
#pragma unroll
        for (int n = 0; n < 2; ++n)
          s[m][n] = __builtin_amdgcn_mfma_f32_16x16x32_bf16(qf[m][ks], kf[n], s[m][n], 0, 0, 0);
    }

    // ---- mask + sigmoid; write attn (fp32, nontemporal) + P (bf16 LDS) ----
#pragma unroll
    for (int m = 0; m < 2; ++m) {
#pragma unroll
      for (int n = 0; n < 2; ++n) {
        int kcol = k0 + wc * 32 + n * 16 + lr;
        int pq0  = wr * 32 + m * 16 + lg * 4;
        int pk   = wc * 32 + n * 16 + lr;
#pragma unroll
        for (int r = 0; r < 4; ++r) {
          float sc = s[m][n][r] * 0.125f;
          float at = 0.0f;
          if (mv[m][n][r] != 0)
            at = __builtin_amdgcn_rcpf(1.0f + __expf(-sc));
          __builtin_nontemporal_store(at, &abase[(size_t)(qrow + m * 16 + lg * 4 + r) * L_ + kcol]);
          int pq = pq0 + r;
          Pl[pq * 64 + (pk ^ ((pq & 7) << 3))] = (unsigned short)b16(at);
        }
      }
    }
    __syncthreads();

    // ---- O += P V (A = P rows wr*32+, B = V^T rows d = wc*32+) ----
#pragma unroll
    for (int ks = 0; ks < 2; ++ks) {
      short8 pf[2], vf[2];
#pragma unroll
      for (int m = 0; m < 2; ++m) {
        int row = wr * 32 + m * 16 + lr;   // q
        int col = ks * 32 + lg * 8;        // k
        pf[m] = *reinterpret_cast<const short8*>(&Pl[row * 64 + (col ^ ((row & 7) << 3))]);
      }
#pragma unroll
      for (int n = 0; n < 2; ++n) {
        int row = wc * 32 + n * 16 + lr;   // d
        int col = ks * 32 + lg * 8;        // k
        vf[n] = *reinterpret_cast<const short8*>(&Vl[row * 64 + (col ^ ((row & 7) << 3))]);
      }
#pragma unroll
      for (int m = 0; m < 2; ++m)
#pragma unroll
        for (int n = 0; n < 2; ++n)
          o[m][n] = __builtin_amdgcn_mfma_f32_16x16x32_bf16(pf[m], vf[n], o[m][n], 0, 0, 0);
    }
  }

  // ---- epilogue: write O ----
  float* obase = O + ((size_t)bh * L_ + (size_t)qt * 64 + wr * 32) * D_;
#pragma unroll
  for (int m = 0; m < 2; ++m)
#pragma unroll
    for (int n = 0; n < 2; ++n)
#pragma unroll
      for (int r = 0; r < 4; ++r)
        __builtin_nontemporal_store(o[m][n][r],
            &obase[(m * 16 + lg * 4 + r) * D_ + wc * 32 + n * 16 + lr]);
}

extern "C" void kernel_launch(void* const* d_in, const int* in_sizes, int n_in,
                              void* d_out, int out_size, void* d_ws, size_t ws_size,
                              hipStream_t stream) {
  (void)in_sizes; (void)n_in; (void)out_size; (void)ws_size;
  const float* Q = (const float*)d_in[0];
  const float* K = (const float*)d_in[1];
  const float* V = (const float*)d_in[2];
  const int*   M = (const int*)d_in[3];
  float* O = (float*)d_out;
  float* A = (float*)d_out + (size_t)BH * L_ * D_;        // attn follows output
  unsigned short* Vt = (unsigned short*)d_ws;             // 16.8 MB scratch

  vt_kernel<<<BH * (L_ / 64), 256, 0, stream>>>(V, Vt);
  attn_kernel<<<BH * (L_ / 64), 256, 0, stream>>>(Q, K, M, Vt, O, A);
}